// Round 1
// baseline (3200.410 us; speedup 1.0000x reference)
//
#include <hip/hip_runtime.h>

#define EMB 64

// Copy user_emb ++ item_emb into cur buffer AND into acc (d_out).
__global__ void concat_init(const float4* __restrict__ ue,
                            const float4* __restrict__ ie,
                            float4* __restrict__ cur,
                            float4* __restrict__ acc,
                            int n_user4, int n_total4) {
    int i = blockIdx.x * blockDim.x + threadIdx.x;
    if (i >= n_total4) return;
    float4 v = (i < n_user4) ? ue[i] : ie[i - n_user4];
    cur[i] = v;
    acc[i] = v;
}

// Edge-parallel SpMM scatter: 16 threads per edge, float4 gather + 4 atomicAdds.
__global__ void spmm_scatter(const int* __restrict__ rows,
                             const int* __restrict__ cols,
                             const float* __restrict__ vals,
                             const float* __restrict__ x,
                             float* __restrict__ y,
                             int n_edges) {
    long long t = (long long)blockIdx.x * blockDim.x + threadIdx.x;
    int e = (int)(t >> 4);
    if (e >= n_edges) return;
    int q = (int)(t & 15);

    int r = rows[e];
    int c = cols[e];
    float v = vals[e];

    const float4* xr = (const float4*)(x + (long long)c * EMB);
    float4 xv = xr[q];

    float* yr = y + (long long)r * EMB + q * 4;
    atomicAdd(yr + 0, v * xv.x);
    atomicAdd(yr + 1, v * xv.y);
    atomicAdd(yr + 2, v * xv.z);
    atomicAdd(yr + 3, v * xv.w);
}

// acc = (acc + nxt) * s   (s = 1 for layers 0,1; s = 0.25 for the last layer)
__global__ void add_scale(float4* __restrict__ acc,
                          const float4* __restrict__ nxt,
                          int n4, float s) {
    int i = blockIdx.x * blockDim.x + threadIdx.x;
    if (i >= n4) return;
    float4 a = acc[i];
    float4 b = nxt[i];
    a.x = (a.x + b.x) * s;
    a.y = (a.y + b.y) * s;
    a.z = (a.z + b.z) * s;
    a.w = (a.w + b.w) * s;
    acc[i] = a;
}

extern "C" void kernel_launch(void* const* d_in, const int* in_sizes, int n_in,
                              void* d_out, int out_size, void* d_ws, size_t ws_size,
                              hipStream_t stream) {
    const float* ue   = (const float*)d_in[0];
    const float* ie   = (const float*)d_in[1];
    const int*   rows = (const int*)d_in[2];
    const int*   cols = (const int*)d_in[3];
    const float* vals = (const float*)d_in[4];
    float* out = (float*)d_out;

    const int num_users = in_sizes[0] / EMB;
    const int num_items = in_sizes[1] / EMB;
    const int n_nodes   = num_users + num_items;
    const int n_edges   = in_sizes[2];

    const size_t buf_elems = (size_t)n_nodes * EMB;   // 9.6M floats = 38.4 MB
    float* buf0 = (float*)d_ws;
    float* buf1 = buf0 + buf_elems;

    const int n_total4 = n_nodes * (EMB / 4);         // 2.4M float4
    const int n_user4  = num_users * (EMB / 4);

    // 1) concat inputs into cur buffer and accumulator (d_out)
    {
        int threads = 256;
        int blocks  = (n_total4 + threads - 1) / threads;
        concat_init<<<blocks, threads, 0, stream>>>(
            (const float4*)ue, (const float4*)ie,
            (float4*)buf0, (float4*)out, n_user4, n_total4);
    }

    float* cur = buf0;
    float* nxt = buf1;

    for (int layer = 0; layer < 3; ++layer) {
        hipMemsetAsync(nxt, 0, buf_elems * sizeof(float), stream);

        {
            long long total_t = (long long)n_edges * 16;
            int threads = 256;
            int blocks  = (int)((total_t + threads - 1) / threads);
            spmm_scatter<<<blocks, threads, 0, stream>>>(
                rows, cols, vals, cur, nxt, n_edges);
        }

        {
            int threads = 256;
            int blocks  = (n_total4 + threads - 1) / threads;
            float s = (layer == 2) ? 0.25f : 1.0f;
            add_scale<<<blocks, threads, 0, stream>>>(
                (float4*)out, (const float4*)nxt, n_total4, s);
        }

        float* t = cur; cur = nxt; nxt = t;
    }
}

// Round 2
// 750.012 us; speedup vs baseline: 4.2671x; 4.2671x over previous
//
#include <hip/hip_runtime.h>

#define EMB 64

// Copy user_emb ++ item_emb into cur buffer AND into acc (d_out).
__global__ void concat_init(const float4* __restrict__ ue,
                            const float4* __restrict__ ie,
                            float4* __restrict__ cur,
                            float4* __restrict__ acc,
                            int n_user4, int n_total4) {
    int i = blockIdx.x * blockDim.x + threadIdx.x;
    if (i >= n_total4) return;
    float4 v = (i < n_user4) ? ue[i] : ie[i - n_user4];
    cur[i] = v;
    acc[i] = v;
}

// Per-row edge counts.
__global__ void histo(const int* __restrict__ rows, int* __restrict__ counts,
                      int n_edges) {
    int e = blockIdx.x * blockDim.x + threadIdx.x;
    if (e < n_edges) atomicAdd(&counts[rows[e]], 1);
}

// Single-workgroup exclusive scan over n counts (n ~ 150K, 1024 threads,
// ~147 elements sequential per thread). counts[] is rewritten in place as
// the fill cursors; row_start[] gets the exclusive prefix + total at [n].
__global__ void scan1024(int* __restrict__ counts,
                         int* __restrict__ row_start, int n) {
    __shared__ int sums[1024];
    int tid = threadIdx.x;
    int chunk = (n + 1023) >> 10;
    int beg = tid * chunk;
    int end = min(beg + chunk, n);
    int s = 0;
    for (int j = beg; j < end; ++j) s += counts[j];
    sums[tid] = s;
    __syncthreads();
    int own = s;
    for (int d = 1; d < 1024; d <<= 1) {
        int t = (tid >= d) ? sums[tid - d] : 0;
        __syncthreads();
        sums[tid] += t;
        __syncthreads();
    }
    int run = sums[tid] - own;  // exclusive prefix of this thread's chunk
    for (int j = beg; j < end; ++j) {
        int c = counts[j];
        row_start[j] = run;
        counts[j] = run;  // becomes the fill cursor for scatter_edges
        run += c;
    }
    if (tid == 1023) row_start[n] = sums[1023];
}

// Scatter (col, val) pairs into row-grouped order.
__global__ void scatter_edges(const int* __restrict__ rows,
                              const int* __restrict__ cols,
                              const float* __restrict__ vals,
                              int* __restrict__ fill,
                              int2* __restrict__ es, int n_edges) {
    int e = blockIdx.x * blockDim.x + threadIdx.x;
    if (e >= n_edges) return;
    int r = rows[e];
    int pos = atomicAdd(&fill[r], 1);
    es[pos] = make_int2(cols[e], __float_as_int(vals[e]));
}

// Row-parallel CSR SpMM, 16 lanes per row (each lane owns a float4 of the
// 64-dim embedding). Fused epilogue: acc += y, and on the last layer
// acc = (acc + y) * 0.25 with no y store.
__global__ void spmm_csr(const int* __restrict__ row_start,
                         const int2* __restrict__ es,
                         const float* __restrict__ x,
                         float4* __restrict__ y,
                         float4* __restrict__ acc,
                         int n_nodes, int last) {
    int gid = blockIdx.x * blockDim.x + threadIdx.x;
    int r = gid >> 4;
    if (r >= n_nodes) return;
    int q = gid & 15;
    int beg = row_start[r];
    int end = row_start[r + 1];
    float4 a = make_float4(0.f, 0.f, 0.f, 0.f);
    for (int j = beg; j < end; ++j) {
        int2 e = es[j];
        float v = __int_as_float(e.y);
        float4 xv = ((const float4*)(x + (size_t)e.x * EMB))[q];
        a.x += v * xv.x;
        a.y += v * xv.y;
        a.z += v * xv.z;
        a.w += v * xv.w;
    }
    size_t o = (size_t)r * (EMB / 4) + q;
    float4 ac = acc[o];
    ac.x += a.x; ac.y += a.y; ac.z += a.z; ac.w += a.w;
    if (last) {
        ac.x *= 0.25f; ac.y *= 0.25f; ac.z *= 0.25f; ac.w *= 0.25f;
    } else {
        y[o] = a;
    }
    acc[o] = ac;
}

extern "C" void kernel_launch(void* const* d_in, const int* in_sizes, int n_in,
                              void* d_out, int out_size, void* d_ws, size_t ws_size,
                              hipStream_t stream) {
    const float* ue   = (const float*)d_in[0];
    const float* ie   = (const float*)d_in[1];
    const int*   rows = (const int*)d_in[2];
    const int*   cols = (const int*)d_in[3];
    const float* vals = (const float*)d_in[4];
    float* out = (float*)d_out;

    const int num_users = in_sizes[0] / EMB;
    const int num_items = in_sizes[1] / EMB;
    const int n_nodes   = num_users + num_items;
    const int n_edges   = in_sizes[2];

    // Workspace layout (~87.6 MB):
    //  buf0, buf1 : ping-pong node embeddings (38.4 MB each)
    //  es         : row-grouped (col,val) pairs (9.6 MB)
    //  row_start  : n_nodes+1 ints
    //  counts/fill: n_nodes ints (histogram, then fill cursors)
    const size_t buf_elems = (size_t)n_nodes * EMB;
    float* buf0 = (float*)d_ws;
    float* buf1 = buf0 + buf_elems;
    int2*  es   = (int2*)(buf1 + buf_elems);
    int*   row_start = (int*)(es + n_edges);
    int*   counts    = row_start + (n_nodes + 1);

    const int n_total4 = n_nodes * (EMB / 4);
    const int n_user4  = num_users * (EMB / 4);

    // 0) zero the histogram
    hipMemsetAsync(counts, 0, (size_t)n_nodes * sizeof(int), stream);

    // 1) concat inputs into cur buffer and accumulator (d_out)
    {
        int threads = 256;
        int blocks  = (n_total4 + threads - 1) / threads;
        concat_init<<<blocks, threads, 0, stream>>>(
            (const float4*)ue, (const float4*)ie,
            (float4*)buf0, (float4*)out, n_user4, n_total4);
    }

    // 2) build row-grouped edge list
    {
        int threads = 256;
        int blocks  = (n_edges + threads - 1) / threads;
        histo<<<blocks, threads, 0, stream>>>(rows, counts, n_edges);
        scan1024<<<1, 1024, 0, stream>>>(counts, row_start, n_nodes);
        scatter_edges<<<blocks, threads, 0, stream>>>(rows, cols, vals,
                                                      counts, es, n_edges);
    }

    // 3) three propagation layers, acc update fused into SpMM epilogue
    float* cur = buf0;
    float* nxt = buf1;
    for (int layer = 0; layer < 3; ++layer) {
        int threads = 256;
        int blocks  = (n_nodes * 16 + threads - 1) / threads;
        spmm_csr<<<blocks, threads, 0, stream>>>(
            row_start, es, cur, (float4*)nxt, (float4*)out,
            n_nodes, layer == 2 ? 1 : 0);
        float* t = cur; cur = nxt; nxt = t;
    }
}

// Round 3
// 433.805 us; speedup vs baseline: 7.3775x; 1.7289x over previous
//
#include <hip/hip_runtime.h>

#define EMB 64

// Copy user_emb ++ item_emb into cur buffer AND into acc (d_out).
__global__ void concat_init(const float4* __restrict__ ue,
                            const float4* __restrict__ ie,
                            float4* __restrict__ cur,
                            float4* __restrict__ acc,
                            int n_user4, int n_total4) {
    int i = blockIdx.x * blockDim.x + threadIdx.x;
    if (i >= n_total4) return;
    float4 v = (i < n_user4) ? ue[i] : ie[i - n_user4];
    cur[i] = v;
    acc[i] = v;
}

// Per-row edge counts.
__global__ void histo(const int* __restrict__ rows, int* __restrict__ counts,
                      int n_edges) {
    int e = blockIdx.x * blockDim.x + threadIdx.x;
    if (e < n_edges) atomicAdd(&counts[rows[e]], 1);
}

// --- hierarchical scan: reduce -> scan block sums -> final scan ---

// Phase A: block b reduces counts[b*1024 .. b*1024+1023] into block_sums[b].
__global__ void scan_reduce(const int* __restrict__ counts,
                            int* __restrict__ block_sums, int n) {
    __shared__ int red[1024];
    int tid = threadIdx.x;
    int i = blockIdx.x * 1024 + tid;
    red[tid] = (i < n) ? counts[i] : 0;
    __syncthreads();
    for (int d = 512; d > 0; d >>= 1) {
        if (tid < d) red[tid] += red[tid + d];
        __syncthreads();
    }
    if (tid == 0) block_sums[blockIdx.x] = red[0];
}

// Phase B: single block exclusive-scans nb (<=1024) block sums in place.
__global__ void scan_blocksums(int* __restrict__ block_sums, int nb) {
    __shared__ int s[1024];
    int tid = threadIdx.x;
    int v = (tid < nb) ? block_sums[tid] : 0;
    s[tid] = v;
    __syncthreads();
    for (int d = 1; d < 1024; d <<= 1) {
        int t = (tid >= d) ? s[tid - d] : 0;
        __syncthreads();
        s[tid] += t;
        __syncthreads();
    }
    if (tid < nb) block_sums[tid] = s[tid] - v;  // exclusive
}

// Phase C: per-block exclusive scan + block offset. Writes row_start and
// rewrites counts[] in place as the fill cursors for scatter_edges.
__global__ void scan_final(int* __restrict__ counts,
                           const int* __restrict__ block_sums,
                           int* __restrict__ row_start, int n) {
    __shared__ int s[1024];
    int tid = threadIdx.x;
    int i = blockIdx.x * 1024 + tid;
    int v = (i < n) ? counts[i] : 0;
    s[tid] = v;
    __syncthreads();
    for (int d = 1; d < 1024; d <<= 1) {
        int t = (tid >= d) ? s[tid - d] : 0;
        __syncthreads();
        s[tid] += t;
        __syncthreads();
    }
    int excl = s[tid] - v + block_sums[blockIdx.x];
    if (i < n) {
        row_start[i] = excl;
        counts[i] = excl;  // fill cursor
        if (i == n - 1) row_start[n] = excl + v;
    }
}

// Scatter (col, val) pairs into row-grouped order.
__global__ void scatter_edges(const int* __restrict__ rows,
                              const int* __restrict__ cols,
                              const float* __restrict__ vals,
                              int* __restrict__ fill,
                              int2* __restrict__ es, int n_edges) {
    int e = blockIdx.x * blockDim.x + threadIdx.x;
    if (e >= n_edges) return;
    int r = rows[e];
    int pos = atomicAdd(&fill[r], 1);
    es[pos] = make_int2(cols[e], __float_as_int(vals[e]));
}

// Row-parallel CSR SpMM, 16 lanes per row (each lane owns a float4 of the
// 64-dim embedding). Fused epilogue: acc += y, and on the last layer
// acc = (acc + y) * 0.25 with no y store.
__global__ void spmm_csr(const int* __restrict__ row_start,
                         const int2* __restrict__ es,
                         const float* __restrict__ x,
                         float4* __restrict__ y,
                         float4* __restrict__ acc,
                         int n_nodes, int last) {
    int gid = blockIdx.x * blockDim.x + threadIdx.x;
    int r = gid >> 4;
    if (r >= n_nodes) return;
    int q = gid & 15;
    int beg = row_start[r];
    int end = row_start[r + 1];
    float4 a = make_float4(0.f, 0.f, 0.f, 0.f);
    for (int j = beg; j < end; ++j) {
        int2 e = es[j];
        float v = __int_as_float(e.y);
        float4 xv = ((const float4*)(x + (size_t)e.x * EMB))[q];
        a.x += v * xv.x;
        a.y += v * xv.y;
        a.z += v * xv.z;
        a.w += v * xv.w;
    }
    size_t o = (size_t)r * (EMB / 4) + q;
    float4 ac = acc[o];
    ac.x += a.x; ac.y += a.y; ac.z += a.z; ac.w += a.w;
    if (last) {
        ac.x *= 0.25f; ac.y *= 0.25f; ac.z *= 0.25f; ac.w *= 0.25f;
    } else {
        y[o] = a;
    }
    acc[o] = ac;
}

extern "C" void kernel_launch(void* const* d_in, const int* in_sizes, int n_in,
                              void* d_out, int out_size, void* d_ws, size_t ws_size,
                              hipStream_t stream) {
    const float* ue   = (const float*)d_in[0];
    const float* ie   = (const float*)d_in[1];
    const int*   rows = (const int*)d_in[2];
    const int*   cols = (const int*)d_in[3];
    const float* vals = (const float*)d_in[4];
    float* out = (float*)d_out;

    const int num_users = in_sizes[0] / EMB;
    const int num_items = in_sizes[1] / EMB;
    const int n_nodes   = num_users + num_items;
    const int n_edges   = in_sizes[2];

    // Workspace layout (~87.6 MB):
    //  buf0, buf1 : ping-pong node embeddings (38.4 MB each)
    //  es         : row-grouped (col,val) pairs (9.6 MB)
    //  row_start  : n_nodes+1 ints
    //  counts/fill: n_nodes ints (histogram, then fill cursors)
    //  block_sums : scan partials
    const size_t buf_elems = (size_t)n_nodes * EMB;
    float* buf0 = (float*)d_ws;
    float* buf1 = buf0 + buf_elems;
    int2*  es   = (int2*)(buf1 + buf_elems);
    int*   row_start  = (int*)(es + n_edges);
    int*   counts     = row_start + (n_nodes + 1);
    int*   block_sums = counts + n_nodes;

    const int n_total4 = n_nodes * (EMB / 4);
    const int n_user4  = num_users * (EMB / 4);
    const int nb_scan  = (n_nodes + 1023) / 1024;   // 147 for 150K nodes

    // 0) zero the histogram
    hipMemsetAsync(counts, 0, (size_t)n_nodes * sizeof(int), stream);

    // 1) concat inputs into cur buffer and accumulator (d_out)
    {
        int threads = 256;
        int blocks  = (n_total4 + threads - 1) / threads;
        concat_init<<<blocks, threads, 0, stream>>>(
            (const float4*)ue, (const float4*)ie,
            (float4*)buf0, (float4*)out, n_user4, n_total4);
    }

    // 2) build row-grouped edge list
    {
        int threads = 256;
        int blocks  = (n_edges + threads - 1) / threads;
        histo<<<blocks, threads, 0, stream>>>(rows, counts, n_edges);
        scan_reduce<<<nb_scan, 1024, 0, stream>>>(counts, block_sums, n_nodes);
        scan_blocksums<<<1, 1024, 0, stream>>>(block_sums, nb_scan);
        scan_final<<<nb_scan, 1024, 0, stream>>>(counts, block_sums,
                                                 row_start, n_nodes);
        scatter_edges<<<blocks, threads, 0, stream>>>(rows, cols, vals,
                                                      counts, es, n_edges);
    }

    // 3) three propagation layers, acc update fused into SpMM epilogue
    float* cur = buf0;
    float* nxt = buf1;
    for (int layer = 0; layer < 3; ++layer) {
        int threads = 256;
        int blocks  = (n_nodes * 16 + threads - 1) / threads;
        spmm_csr<<<blocks, threads, 0, stream>>>(
            row_start, es, cur, (float4*)nxt, (float4*)out,
            n_nodes, layer == 2 ? 1 : 0);
        float* t = cur; cur = nxt; nxt = t;
    }
}